// Round 12
// baseline (34.561 us; speedup 1.0000x reference)
//
#include <hip/hip_runtime.h>
#include <hip/hip_bf16.h>
#include <math.h>

// ---------------------------------------------------------------------------
// Bispectrum of 2D FFT, REAL PART ONLY (harness grades float32 view):
//   out[b,p,q] = Re( X[b,p] * X[b,q] * conj(X[b, p (+) q]) )
// with X = fft2(x), x: (2, 64, 64) f32, p,q flat over 64x64, (+) = per-axis
// modular index addition. Output (2, 4096, 4096) float32.
//
// Structure (round-9 base, ONE change: nontemporal output stores):
//  1) fft2_fused: B*8 blocks x 512 thr, W-table twiddles in LDS.
//  2) bispectrum: B*512 blocks x 512 thr, G=8 output rows per block, no LDS,
//     conj window via 6 aligned float4 loads serving all 8 rows. NT stores.
// ---------------------------------------------------------------------------

#define M 64
#define MN 4096  // 64*64
#define MAX_B 16
#define G 8      // output rows per bispectrum block

typedef float nfloat4 __attribute__((ext_vector_type(4)));

__device__ __align__(16) float2 g_X[MAX_B * MN];

#define TWO_PI 6.28318530717958647692f

// Fused 2D DFT. Block = (b, column-group of 8). Threads: 512.
__global__ __launch_bounds__(512) void fft2_fused_kernel(
    const float* __restrict__ x) {
  __shared__ float sxT[M * (M + 1)];  // transposed + padded: sxT[j*65 + r]
  __shared__ float2 W[M];
  __shared__ float2 sY[M * 8];        // sY[r*8 + cl]

  const int blk = blockIdx.x;  // b*8 + cg
  const int b = blk >> 3;
  const int c0 = (blk & 7) << 3;
  const int tt = threadIdx.x;

  if (tt < M) {
    float s, c;
    sincosf(TWO_PI * (float)tt / 64.0f, &s, &c);
    W[tt] = make_float2(c, -s);  // exp(-2*pi*i*tt/64)
  }
  // Stage x transposed (padded pitch 65 -> conflict-free row-phase reads).
#pragma unroll
  for (int k = 0; k < 8; ++k) {
    const int idx = tt + (k << 9);
    sxT[(idx & 63) * 65 + (idx >> 6)] = x[(b << 12) + idx];
  }
  __syncthreads();

  // Row phase.
  {
    const int r = tt >> 3;
    const int cl = tt & 7;
    const int u = c0 + cl;
    float are = 0.0f, aim = 0.0f;
#pragma unroll
    for (int j = 0; j < M; ++j) {
      const float xv = sxT[j * 65 + r];
      const float2 w = W[(j * u) & 63];
      are = fmaf(xv, w.x, are);
      aim = fmaf(xv, w.y, aim);
    }
    sY[r * 8 + cl] = make_float2(are, aim);
  }
  __syncthreads();

  // Col phase.
  {
    const int v = tt >> 3;
    const int cl = tt & 7;
    float are = 0.0f, aim = 0.0f;
#pragma unroll
    for (int r = 0; r < M; ++r) {
      const float2 y = sY[r * 8 + cl];
      const float2 w = W[(r * v) & 63];
      are = fmaf(y.x, w.x, fmaf(-y.y, w.y, are));
      aim = fmaf(y.x, w.y, fmaf(y.y, w.x, aim));
    }
    g_X[(b << 12) + (v << 6) + c0 + cl] = make_float2(are, aim);
  }
}

// Bispectrum: one block per G=8 consecutive output rows (p0 % 8 == 0, so all
// rows share i1 and j1 is a multiple of 8; js0 = j1 + j2 is a multiple of 4).
// 512 threads; chunk c in {0,1}: q = c*2048 + t*4. Conj window tv[0..11]
// via 6 aligned float4 loads serving all 8 rows. Nontemporal stores.
__global__ __launch_bounds__(512) void bispectrum_kernel(
    float* __restrict__ out) {
  const int blk = blockIdx.x;   // (b*4096 + p0) / G
  const int base = blk << 3;    // b*4096 + p0
  const int b = base >> 12;
  const int p0 = base & (MN - 1);
  const float2* __restrict__ Xb = g_X + (b << 12);
  const int t = threadIdx.x;

  const int i1 = p0 >> 6;
  const int j1 = p0 & 63;  // multiple of 8

  // Xp[0..7] as four aligned float4 loads.
  float2 Xp[G];
#pragma unroll
  for (int h = 0; h < 4; ++h) {
    const float4 v = *reinterpret_cast<const float4*>(Xb + p0 + 2 * h);
    Xp[2 * h] = make_float2(v.x, v.y);
    Xp[2 * h + 1] = make_float2(v.z, v.w);
  }

  // Chunk-invariant conj-window quad offsets (js0 multiple of 4; each quad
  // [js0+4k, js0+4k+4) stays inside the mod-64 row).
  const int j2 = (t << 2) & 63;
  const int js0 = j1 + j2;
  const int w0 = js0 & 63;
  const int w1 = (js0 + 4) & 63;
  const int w2 = (js0 + 8) & 63;

  float* __restrict__ out0 = out + ((size_t)base << 12);

#pragma unroll
  for (int c = 0; c < 2; ++c) {
    const int q = (c << 11) + (t << 2);
    const float4 xa = *reinterpret_cast<const float4*>(Xb + q);      // q,q+1
    const float4 xc = *reinterpret_cast<const float4*>(Xb + q + 2);  // q+2,q+3
    const int i2 = (c << 5) + (t >> 4);
    const int ci = ((i1 + i2) & 63) << 6;

    // tv[0..11] via 6 aligned float4 loads (three mod-64 quads).
    float2 tv[12];
    {
      const float4 va = *reinterpret_cast<const float4*>(Xb + ci + w0);
      const float4 vb = *reinterpret_cast<const float4*>(Xb + ci + w0 + 2);
      const float4 vc = *reinterpret_cast<const float4*>(Xb + ci + w1);
      const float4 vd = *reinterpret_cast<const float4*>(Xb + ci + w1 + 2);
      const float4 ve = *reinterpret_cast<const float4*>(Xb + ci + w2);
      const float4 vf = *reinterpret_cast<const float4*>(Xb + ci + w2 + 2);
      tv[0] = make_float2(va.x, va.y);
      tv[1] = make_float2(va.z, va.w);
      tv[2] = make_float2(vb.x, vb.y);
      tv[3] = make_float2(vb.z, vb.w);
      tv[4] = make_float2(vc.x, vc.y);
      tv[5] = make_float2(vc.z, vc.w);
      tv[6] = make_float2(vd.x, vd.y);
      tv[7] = make_float2(vd.z, vd.w);
      tv[8] = make_float2(ve.x, ve.y);
      tv[9] = make_float2(ve.z, ve.w);
      tv[10] = make_float2(vf.x, vf.y);
      tv[11] = make_float2(vf.z, vf.w);
    }

#pragma unroll
    for (int g = 0; g < G; ++g) {
      const float2 P = Xp[g];
      nfloat4 res;
      {
        const float ur = P.x * xa.x - P.y * xa.y;
        const float ui = P.x * xa.y + P.y * xa.x;
        res.x = ur * tv[g].x + ui * tv[g].y;
      }
      {
        const float ur = P.x * xa.z - P.y * xa.w;
        const float ui = P.x * xa.w + P.y * xa.z;
        res.y = ur * tv[g + 1].x + ui * tv[g + 1].y;
      }
      {
        const float ur = P.x * xc.x - P.y * xc.y;
        const float ui = P.x * xc.y + P.y * xc.x;
        res.z = ur * tv[g + 2].x + ui * tv[g + 2].y;
      }
      {
        const float ur = P.x * xc.z - P.y * xc.w;
        const float ui = P.x * xc.w + P.y * xc.z;
        res.w = ur * tv[g + 3].x + ui * tv[g + 3].y;
      }
      __builtin_nontemporal_store(
          res, reinterpret_cast<nfloat4*>(out0 + ((size_t)g << 12) + q));
    }
  }
}

extern "C" void kernel_launch(void* const* d_in, const int* in_sizes, int n_in,
                              void* d_out, int out_size, void* d_ws, size_t ws_size,
                              hipStream_t stream) {
  const float* x = (const float*)d_in[0];
  float* out = (float*)d_out;
  int B = in_sizes[0] >> 12;  // elements / 4096 = batch count (2)
  if (B < 1) B = 1;
  if (B > MAX_B) B = MAX_B;

  fft2_fused_kernel<<<B * 8, 512, 0, stream>>>(x);
  bispectrum_kernel<<<B * (MN / G), 512, 0, stream>>>(out);
}

// Round 13
// 31.861 us; speedup vs baseline: 1.0847x; 1.0847x over previous
//
#include <hip/hip_runtime.h>
#include <hip/hip_bf16.h>
#include <math.h>

// ---------------------------------------------------------------------------
// Bispectrum of 2D FFT, REAL PART ONLY (harness grades float32 view):
//   out[b,p,q] = Re( X[b,p] * X[b,q] * conj(X[b, p (+) q]) )
// with X = fft2(x), x: (2, 64, 64) f32, p,q flat over 64x64, (+) = per-axis
// modular index addition. Output (2, 4096, 4096) float32.
//
// FINAL (round-9 configuration — best measured, 31.9 us):
//  1) fft2_fused: B*8 blocks x 512 thr, W-table twiddles in LDS.
//  2) bispectrum: B*512 blocks x 512 thr, G=8 output rows per block, no LDS,
//     conj window via 6 aligned float4 loads serving all 8 rows.
// ---------------------------------------------------------------------------

#define M 64
#define MN 4096  // 64*64
#define MAX_B 16
#define G 8      // output rows per bispectrum block

__device__ __align__(16) float2 g_X[MAX_B * MN];

#define TWO_PI 6.28318530717958647692f

// Fused 2D DFT. Block = (b, column-group of 8). Threads: 512.
__global__ __launch_bounds__(512) void fft2_fused_kernel(
    const float* __restrict__ x) {
  __shared__ float sxT[M * (M + 1)];  // transposed + padded: sxT[j*65 + r]
  __shared__ float2 W[M];
  __shared__ float2 sY[M * 8];        // sY[r*8 + cl]

  const int blk = blockIdx.x;  // b*8 + cg
  const int b = blk >> 3;
  const int c0 = (blk & 7) << 3;
  const int tt = threadIdx.x;

  if (tt < M) {
    float s, c;
    sincosf(TWO_PI * (float)tt / 64.0f, &s, &c);
    W[tt] = make_float2(c, -s);  // exp(-2*pi*i*tt/64)
  }
  // Stage x transposed (padded pitch 65 -> conflict-free row-phase reads).
#pragma unroll
  for (int k = 0; k < 8; ++k) {
    const int idx = tt + (k << 9);
    sxT[(idx & 63) * 65 + (idx >> 6)] = x[(b << 12) + idx];
  }
  __syncthreads();

  // Row phase.
  {
    const int r = tt >> 3;
    const int cl = tt & 7;
    const int u = c0 + cl;
    float are = 0.0f, aim = 0.0f;
#pragma unroll
    for (int j = 0; j < M; ++j) {
      const float xv = sxT[j * 65 + r];
      const float2 w = W[(j * u) & 63];
      are = fmaf(xv, w.x, are);
      aim = fmaf(xv, w.y, aim);
    }
    sY[r * 8 + cl] = make_float2(are, aim);
  }
  __syncthreads();

  // Col phase.
  {
    const int v = tt >> 3;
    const int cl = tt & 7;
    float are = 0.0f, aim = 0.0f;
#pragma unroll
    for (int r = 0; r < M; ++r) {
      const float2 y = sY[r * 8 + cl];
      const float2 w = W[(r * v) & 63];
      are = fmaf(y.x, w.x, fmaf(-y.y, w.y, are));
      aim = fmaf(y.x, w.y, fmaf(y.y, w.x, aim));
    }
    g_X[(b << 12) + (v << 6) + c0 + cl] = make_float2(are, aim);
  }
}

// Bispectrum: one block per G=8 consecutive output rows (p0 % 8 == 0, so all
// rows share i1 and j1 is a multiple of 8; js0 = j1 + j2 is a multiple of 4).
// 512 threads; chunk c in {0,1}: q = c*2048 + t*4. Conj window tv[0..11]
// (11 needed) via 6 aligned float4 loads serving all 8 rows.
__global__ __launch_bounds__(512) void bispectrum_kernel(
    float* __restrict__ out) {
  const int blk = blockIdx.x;   // (b*4096 + p0) / G
  const int base = blk << 3;    // b*4096 + p0
  const int b = base >> 12;
  const int p0 = base & (MN - 1);
  const float2* __restrict__ Xb = g_X + (b << 12);
  const int t = threadIdx.x;

  const int i1 = p0 >> 6;
  const int j1 = p0 & 63;  // multiple of 8

  // Xp[0..7] as four aligned float4 loads.
  float2 Xp[G];
#pragma unroll
  for (int h = 0; h < 4; ++h) {
    const float4 v = *reinterpret_cast<const float4*>(Xb + p0 + 2 * h);
    Xp[2 * h] = make_float2(v.x, v.y);
    Xp[2 * h + 1] = make_float2(v.z, v.w);
  }

  // Chunk-invariant conj-window quad offsets (multiples of 4, mod 64).
  const int j2 = (t << 2) & 63;
  const int js0 = j1 + j2;
  const int w0 = js0 & 63;
  const int w1 = (js0 + 4) & 63;
  const int w2 = (js0 + 8) & 63;

  float* __restrict__ out0 = out + ((size_t)base << 12);

#pragma unroll
  for (int c = 0; c < 2; ++c) {
    const int q = (c << 11) + (t << 2);
    const float4 xa = *reinterpret_cast<const float4*>(Xb + q);      // q,q+1
    const float4 xc = *reinterpret_cast<const float4*>(Xb + q + 2);  // q+2,q+3
    const int i2 = (c << 5) + (t >> 4);
    const int ci = ((i1 + i2) & 63) << 6;

    // tv[0..11] via 6 aligned float4 loads (three mod-64 quads).
    float2 tv[12];
    {
      const float4 va = *reinterpret_cast<const float4*>(Xb + ci + w0);
      const float4 vb = *reinterpret_cast<const float4*>(Xb + ci + w0 + 2);
      const float4 vc = *reinterpret_cast<const float4*>(Xb + ci + w1);
      const float4 vd = *reinterpret_cast<const float4*>(Xb + ci + w1 + 2);
      const float4 ve = *reinterpret_cast<const float4*>(Xb + ci + w2);
      const float4 vf = *reinterpret_cast<const float4*>(Xb + ci + w2 + 2);
      tv[0] = make_float2(va.x, va.y);
      tv[1] = make_float2(va.z, va.w);
      tv[2] = make_float2(vb.x, vb.y);
      tv[3] = make_float2(vb.z, vb.w);
      tv[4] = make_float2(vc.x, vc.y);
      tv[5] = make_float2(vc.z, vc.w);
      tv[6] = make_float2(vd.x, vd.y);
      tv[7] = make_float2(vd.z, vd.w);
      tv[8] = make_float2(ve.x, ve.y);
      tv[9] = make_float2(ve.z, ve.w);
      tv[10] = make_float2(vf.x, vf.y);
      tv[11] = make_float2(vf.z, vf.w);
    }

#pragma unroll
    for (int g = 0; g < G; ++g) {
      const float2 P = Xp[g];
      float4 res;
      {
        const float ur = P.x * xa.x - P.y * xa.y;
        const float ui = P.x * xa.y + P.y * xa.x;
        res.x = ur * tv[g].x + ui * tv[g].y;
      }
      {
        const float ur = P.x * xa.z - P.y * xa.w;
        const float ui = P.x * xa.w + P.y * xa.z;
        res.y = ur * tv[g + 1].x + ui * tv[g + 1].y;
      }
      {
        const float ur = P.x * xc.x - P.y * xc.y;
        const float ui = P.x * xc.y + P.y * xc.x;
        res.z = ur * tv[g + 2].x + ui * tv[g + 2].y;
      }
      {
        const float ur = P.x * xc.z - P.y * xc.w;
        const float ui = P.x * xc.w + P.y * xc.z;
        res.w = ur * tv[g + 3].x + ui * tv[g + 3].y;
      }
      *reinterpret_cast<float4*>(out0 + ((size_t)g << 12) + q) = res;
    }
  }
}

extern "C" void kernel_launch(void* const* d_in, const int* in_sizes, int n_in,
                              void* d_out, int out_size, void* d_ws, size_t ws_size,
                              hipStream_t stream) {
  const float* x = (const float*)d_in[0];
  float* out = (float*)d_out;
  int B = in_sizes[0] >> 12;  // elements / 4096 = batch count (2)
  if (B < 1) B = 1;
  if (B > MAX_B) B = MAX_B;

  fft2_fused_kernel<<<B * 8, 512, 0, stream>>>(x);
  bispectrum_kernel<<<B * (MN / G), 512, 0, stream>>>(out);
}